// Round 11
// baseline (198.190 us; speedup 1.0000x reference)
//
#include <hip/hip_runtime.h>
#include <hip/hip_fp16.h>
#include <math.h>

#define N_NODES 50000
#define N_EDGES 1600000
#define N_GRAPHS 512
#define HID 32
#define NEG_SLOPE 0.2f
#define SM_EPS 1e-16f
#define PAD 80          // max in-degree slots; dst~Poisson(32), P(deg>=80)*N ~ 5e-7
#define NBIN 261        // one bin per k_asm_gather block
#define BIN_W 192       // nodes per bin (192*80*4B = 61.4 KB LDS rows)
#define BIN_CAP 7100    // 6144 mean + ~12 sigma
#define EPT 10          // edges per thread in k_part_direct
#define PART_BLOCKS 625 // 625 * 256 * 10 = 1,600,000 exactly

// ---------------- kernel 1: fused histogram + global-base + ranked scatter ----------------
__global__ __launch_bounds__(256) void k_part_direct(const int* __restrict__ ei,
                                                     const float* __restrict__ ea,
                                                     const float* __restrict__ W_edge,
                                                     const float* __restrict__ att_edge,
                                                     uint2* __restrict__ part,
                                                     int* __restrict__ pcur) {
    __shared__ float sv[3];
    __shared__ int lcnt[NBIN], lcur[NBIN];
    int t = threadIdx.x;
    if (t < 3) {
        float v = 0.f;
        for (int j = 0; j < 32; ++j) v += W_edge[t * 32 + j] * att_edge[j];
        sv[t] = v;
    }
    for (int i = t; i < NBIN; i += 256) lcnt[i] = 0;
    __syncthreads();

    uint2 r[EPT];
    int bin[EPT];
    int ebase = blockIdx.x * (256 * EPT) + t;
#pragma unroll
    for (int i = 0; i < EPT; ++i) {
        int e = ebase + i * 256;
        int s = ei[e];
        int d = ei[N_EDGES + e];
        float aev = ea[e * 3 + 0] * sv[0] + ea[e * 3 + 1] * sv[1] + ea[e * 3 + 2] * sv[2];
        r[i] = make_uint2((unsigned)d | ((unsigned)s << 16), __float_as_uint(aev));
        bin[i] = d / BIN_W;
        atomicAdd(&lcnt[bin[i]], 1);
    }
    __syncthreads();
    for (int i = t; i < NBIN; i += 256) lcur[i] = atomicAdd(pcur + i, lcnt[i]);
    __syncthreads();
#pragma unroll
    for (int i = 0; i < EPT; ++i) {
        int pos = atomicAdd(&lcur[bin[i]], 1);
        if (pos < BIN_CAP) part[(size_t)bin[i] * BIN_CAP + pos] = r[i];
    }
}

// ---------------- kernel 2: node transform h = x@W (fp16 out), a_src, a_dst ----------------
__global__ void k_node(const float* __restrict__ x, const float* __restrict__ W,
                       const float* __restrict__ att_src, const float* __restrict__ att_dst,
                       __half2* __restrict__ h2, float* __restrict__ a_src,
                       float* __restrict__ a_dst) {
    __shared__ float sW[12 * 32];
    __shared__ float sas[32], sad[32];
    int t = threadIdx.x;
    for (int i = t; i < 12 * 32; i += blockDim.x) sW[i] = W[i];
    if (t < 32) { sas[t] = att_src[t]; sad[t] = att_dst[t]; }
    __syncthreads();
    int n = blockIdx.x * blockDim.x + t;
    if (n >= N_NODES) return;

    float xv[12];
#pragma unroll
    for (int j = 0; j < 12; ++j) xv[j] = x[n * 12 + j];

    float hv[32];
    float as = 0.f, ad = 0.f;
#pragma unroll
    for (int k = 0; k < 32; ++k) {
        float acc = 0.f;
#pragma unroll
        for (int j = 0; j < 12; ++j) acc += xv[j] * sW[j * 32 + k];
        hv[k] = acc;
        as += acc * sas[k];
        ad += acc * sad[k];
    }
    a_src[n] = as;
    a_dst[n] = ad;

    __half2 hp[16];
#pragma unroll
    for (int k = 0; k < 16; ++k) hp[k] = __floats2half2_rn(hv[2 * k], hv[2 * k + 1]);
    uint4* dst = (uint4*)(h2 + (size_t)n * 16);
    const uint4* srcp = (const uint4*)hp;
#pragma unroll
    for (int k = 0; k < 4; ++k) dst[k] = srcp[k];
}

// ---------------- kernel 3: fused LDS row assembly + gather; bin == block ----------------
// Lane map: es = l>>4 (0..3, edge subgroup), cg = l&15 (2 channels each, half2).
// Reduction: only 2 xor levels (masks 16,32) over 4 accumulators = 8 shfl/node.
__global__ __launch_bounds__(1024) void k_asm_gather(const uint2* __restrict__ part,
                                                     const int* __restrict__ pcur,
                                                     const __half2* __restrict__ h2,
                                                     const float* __restrict__ a_src,
                                                     const float* __restrict__ a_dst,
                                                     const float* __restrict__ bias,
                                                     const float* __restrict__ W_gate,
                                                     const float* __restrict__ b_gate,
                                                     float* __restrict__ oacc,
                                                     float* __restrict__ ge) {
    int b = blockIdx.x;
    int lo = b * BIN_W;
    int hi = lo + BIN_W; if (hi > N_NODES) hi = N_NODES;
    int nrow = hi - lo;
    __shared__ int lcur[BIN_W];
    __shared__ unsigned lbuck[BIN_W * PAD];   // 61.4 KB
    int t = threadIdx.x;
    if (t < BIN_W) lcur[t] = 0;
    __syncthreads();

    // ---- phase 1: assemble rows in LDS (own partition only, read once) ----
    int cnt = pcur[b]; if (cnt > BIN_CAP) cnt = BIN_CAP;
    const uint2* p = part + (size_t)b * BIN_CAP;
    for (int i = t; i < cnt; i += 1024) {
        uint2 r = p[i];
        int li = (int)(r.x & 0xFFFF) - lo;
        unsigned s = r.x >> 16;
        unsigned short hb = __half_as_ushort(__float2half_rn(__uint_as_float(r.y)));
        int pos = atomicAdd(&lcur[li], 1);
        if (pos < PAD) lbuck[li * PAD + pos] = s | ((unsigned)hb << 16);
    }
    __syncthreads();

    // ---- phase 2: wave-per-node gather ----
    int l = t & 63, wl = t >> 6;   // 16 waves
    int es = l >> 4;               // 0..3
    int cg = l & 15;               // 0..15, channels 2cg, 2cg+1

    for (int li = wl; li < nrow; li += 16) {
        int n = lo + li;
        int deg_full = lcur[li];
        int degc = deg_full < PAD ? deg_full : PAD;
        float adst_n = a_dst[n];
        const unsigned* row = lbuck + li * PAD;

        float c0 = 0.f, c1 = 0.f, wsum = 0.f, aevsum = 0.f;
        int j = es;
        for (; j + 4 < degc; j += 8) {
            unsigned p0 = row[j], p1 = row[j + 4];
            int s0 = p0 & 0xFFFF, s1 = p1 & 0xFFFF;
            float aev0 = __half2float(__ushort_as_half((unsigned short)(p0 >> 16)));
            float aev1 = __half2float(__ushort_as_half((unsigned short)(p1 >> 16)));
            float as0 = a_src[s0], as1 = a_src[s1];
            float2 f0 = __half22float2(h2[(size_t)s0 * 16 + cg]);
            float2 f1 = __half22float2(h2[(size_t)s1 * 16 + cg]);
            float a0 = as0 + adst_n + aev0; a0 = a0 > 0.f ? a0 : NEG_SLOPE * a0;
            float a1 = as1 + adst_n + aev1; a1 = a1 > 0.f ? a1 : NEG_SLOPE * a1;
            float w0 = __expf(a0), w1 = __expf(a1);
            wsum += w0 + w1; aevsum += aev0 + aev1;
            c0 += w0 * f0.x + w1 * f1.x;
            c1 += w0 * f0.y + w1 * f1.y;
        }
        if (j < degc) {
            unsigned p0 = row[j];
            int s0 = p0 & 0xFFFF;
            float aev0 = __half2float(__ushort_as_half((unsigned short)(p0 >> 16)));
            float a0 = a_src[s0] + adst_n + aev0; a0 = a0 > 0.f ? a0 : NEG_SLOPE * a0;
            float w0 = __expf(a0);
            float2 f0 = __half22float2(h2[(size_t)s0 * 16 + cg]);
            wsum += w0; aevsum += aev0;
            c0 += w0 * f0.x; c1 += w0 * f0.y;
        }

        // reduce over es (lanes sharing cg): xor 16, 32 — 8 shfl total
        c0 += __shfl_xor(c0, 16); c1 += __shfl_xor(c1, 16);
        wsum += __shfl_xor(wsum, 16); aevsum += __shfl_xor(aevsum, 16);
        c0 += __shfl_xor(c0, 32); c1 += __shfl_xor(c1, 32);
        wsum += __shfl_xor(wsum, 32); aevsum += __shfl_xor(aevsum, 32);

        float dgm = deg_full > 1 ? (float)deg_full : 1.f;
        float al = a_src[n] + adst_n + aevsum / dgm;
        al = al > 0.f ? al : NEG_SLOPE * al;
        float el = __expf(al);
        float zi = 1.f / (wsum + el + SM_EPS);

        if (es == 0) {          // lanes 0..15, 2 channels each
            float2 hn = __half22float2(h2[(size_t)n * 16 + cg]);
            float2 bv = *(const float2*)(bias + cg * 2);
            float v0 = (c0 + el * hn.x) * zi + bv.x;
            float v1 = (c1 + el * hn.y) * zi + bv.y;
            v0 = v0 > 0.f ? v0 : 0.f;
            v1 = v1 > 0.f ? v1 : 0.f;
            *(float2*)(oacc + (size_t)n * 32 + cg * 2) = make_float2(v0, v1);
            float2 wg = *(const float2*)(W_gate + cg * 2);
            float g = v0 * wg.x + v1 * wg.y;
            g += __shfl_xor(g, 1);
            g += __shfl_xor(g, 2);
            g += __shfl_xor(g, 4);
            g += __shfl_xor(g, 8);
            if (cg == 0) {
                g += b_gate[0];
                ge[n] = __expf(g);
            }
        }
    }
}

// ---------------- kernel 4: per-graph pooling + output head (inline boundary search) ----------------
__global__ __launch_bounds__(256) void k_pool_out(const float* __restrict__ oacc,
                                                  const float* __restrict__ ge,
                                                  const int* __restrict__ batch,
                                                  const float* __restrict__ W_out,
                                                  const float* __restrict__ b_out,
                                                  float* __restrict__ out) {
    int g = blockIdx.x;
    int t = threadIdx.x;
    __shared__ int sbound[2];
    if (t < 2) {
        int target = g + t;
        int lo = 0, hi = N_NODES;
        if (target >= N_GRAPHS) lo = N_NODES;
        else {
            while (lo < hi) {
                int mid = (lo + hi) >> 1;
                if (batch[mid] < target) lo = mid + 1; else hi = mid;
            }
        }
        sbound[t] = lo;
    }
    __syncthreads();
    int beg = sbound[0], end = sbound[1];
    __shared__ float swz[4];
    __shared__ float part[8][32];
    __shared__ float sgz;

    float s = 0.f;
    for (int n = beg + t; n < end; n += 256) s += ge[n];
#pragma unroll
    for (int ofs = 32; ofs > 0; ofs >>= 1) s += __shfl_down(s, ofs);
    if ((t & 63) == 0) swz[t >> 6] = s;
    __syncthreads();
    if (t == 0) sgz = swz[0] + swz[1] + swz[2] + swz[3];
    __syncthreads();
    float gz = sgz;

    int c = t & 31, ng = t >> 5;
    float acc = 0.f;
    for (int n = beg + ng; n < end; n += 8)
        acc += oacc[(size_t)n * 32 + c] * ge[n];
    part[ng][c] = acc;
    __syncthreads();
    if (t < 32) {
        float p = 0.f;
#pragma unroll
        for (int i = 0; i < 8; ++i) p += part[i][t];
        p /= (gz + SM_EPS);
        float o = p * W_out[t];
#pragma unroll
        for (int ofs = 16; ofs > 0; ofs >>= 1) o += __shfl_down(o, ofs);
        if (t == 0) out[g] = 1.f / (1.f + __expf(-(o + b_out[0])));
    }
}

extern "C" void kernel_launch(void* const* d_in, const int* in_sizes, int n_in,
                              void* d_out, int out_size, void* d_ws, size_t ws_size,
                              hipStream_t stream) {
    const float* x        = (const float*)d_in[0];
    const int*   ei       = (const int*)  d_in[1];
    const float* ea       = (const float*)d_in[2];
    const int*   batch    = (const int*)  d_in[3];
    const float* W        = (const float*)d_in[4];
    const float* att_src  = (const float*)d_in[5];
    const float* att_dst  = (const float*)d_in[6];
    const float* W_edge   = (const float*)d_in[7];
    const float* att_edge = (const float*)d_in[8];
    const float* bias     = (const float*)d_in[9];
    const float* W_gate   = (const float*)d_in[10];
    const float* b_gate   = (const float*)d_in[11];
    const float* W_out    = (const float*)d_in[12];
    const float* b_out    = (const float*)d_in[13];
    float* out = (float*)d_out;

    // workspace layout
    char* wsb = (char*)d_ws;
    uint2*    part_  = (uint2*)wsb;                                // NBIN*BIN_CAP uint2 = 14.8 MB
    __half2*  h2     = (__half2*)(part_ + (size_t)NBIN * BIN_CAP); // 16N half2 = 3.2 MB
    float*    a_src  = (float*)(h2 + (size_t)16 * N_NODES);        // N
    float*    a_dst  = a_src + N_NODES;                            // N
    float*    ge     = a_dst + N_NODES;                            // N
    float*    oacc   = ge + N_NODES;                               // 32N
    int*      pcur   = (int*)(oacc + (size_t)32 * N_NODES);        // NBIN (zeroed)

    hipMemsetAsync(pcur, 0, NBIN * sizeof(int), stream);

    const int B = 256;
    k_part_direct<<<PART_BLOCKS, B, 0, stream>>>(ei, ea, W_edge, att_edge, part_, pcur);
    k_node<<<(N_NODES + B - 1) / B, B, 0, stream>>>(x, W, att_src, att_dst, h2, a_src, a_dst);
    k_asm_gather<<<NBIN, 1024, 0, stream>>>(part_, pcur, h2, a_src, a_dst, bias,
                                            W_gate, b_gate, oacc, ge);
    k_pool_out<<<N_GRAPHS, B, 0, stream>>>(oacc, ge, batch, W_out, b_out, out);
}

// Round 12
// 172.246 us; speedup vs baseline: 1.1506x; 1.1506x over previous
//
#include <hip/hip_runtime.h>
#include <hip/hip_fp16.h>
#include <math.h>

#define N_NODES 50000
#define N_EDGES 1600000
#define N_GRAPHS 512
#define HID 32
#define NEG_SLOPE 0.2f
#define SM_EPS 1e-16f
#define PAD 80          // max in-degree slots; dst~Poisson(32), P(deg>=80)*N ~ 5e-7
#define NBIN 511        // one bin per k_asm_gather block (ceil(50000/98))
#define BIN_W 98        // nodes per bin -> 98*80*4B = 31.4 KB LDS rows -> 2 blocks/CU
#define BIN_CAP 3800    // 3130 mean + ~12 sigma
#define EPT 10          // edges per thread in k_part_direct
#define PART_BLOCKS 625 // 625 * 256 * 10 = 1,600,000 exactly

// ---------------- kernel 1: fused histogram + global-base + ranked scatter ----------------
__global__ __launch_bounds__(256) void k_part_direct(const int* __restrict__ ei,
                                                     const float* __restrict__ ea,
                                                     const float* __restrict__ W_edge,
                                                     const float* __restrict__ att_edge,
                                                     uint2* __restrict__ part,
                                                     int* __restrict__ pcur) {
    __shared__ float sv[3];
    __shared__ int lcnt[NBIN], lcur[NBIN];
    int t = threadIdx.x;
    if (t < 3) {
        float v = 0.f;
        for (int j = 0; j < 32; ++j) v += W_edge[t * 32 + j] * att_edge[j];
        sv[t] = v;
    }
    for (int i = t; i < NBIN; i += 256) lcnt[i] = 0;
    __syncthreads();

    uint2 r[EPT];
    int bin[EPT];
    int ebase = blockIdx.x * (256 * EPT) + t;
#pragma unroll
    for (int i = 0; i < EPT; ++i) {
        int e = ebase + i * 256;
        int s = ei[e];
        int d = ei[N_EDGES + e];
        float aev = ea[e * 3 + 0] * sv[0] + ea[e * 3 + 1] * sv[1] + ea[e * 3 + 2] * sv[2];
        r[i] = make_uint2((unsigned)d | ((unsigned)s << 16), __float_as_uint(aev));
        bin[i] = d / BIN_W;
        atomicAdd(&lcnt[bin[i]], 1);
    }
    __syncthreads();
    for (int i = t; i < NBIN; i += 256) lcur[i] = atomicAdd(pcur + i, lcnt[i]);
    __syncthreads();
#pragma unroll
    for (int i = 0; i < EPT; ++i) {
        int pos = atomicAdd(&lcur[bin[i]], 1);
        if (pos < BIN_CAP) part[(size_t)bin[i] * BIN_CAP + pos] = r[i];
    }
}

// ---------------- kernel 2: node transform h = x@W (fp16 out), a_src, a_dst ----------------
__global__ void k_node(const float* __restrict__ x, const float* __restrict__ W,
                       const float* __restrict__ att_src, const float* __restrict__ att_dst,
                       __half2* __restrict__ h2, float* __restrict__ a_src,
                       float* __restrict__ a_dst) {
    __shared__ float sW[12 * 32];
    __shared__ float sas[32], sad[32];
    int t = threadIdx.x;
    for (int i = t; i < 12 * 32; i += blockDim.x) sW[i] = W[i];
    if (t < 32) { sas[t] = att_src[t]; sad[t] = att_dst[t]; }
    __syncthreads();
    int n = blockIdx.x * blockDim.x + t;
    if (n >= N_NODES) return;

    float xv[12];
#pragma unroll
    for (int j = 0; j < 12; ++j) xv[j] = x[n * 12 + j];

    float hv[32];
    float as = 0.f, ad = 0.f;
#pragma unroll
    for (int k = 0; k < 32; ++k) {
        float acc = 0.f;
#pragma unroll
        for (int j = 0; j < 12; ++j) acc += xv[j] * sW[j * 32 + k];
        hv[k] = acc;
        as += acc * sas[k];
        ad += acc * sad[k];
    }
    a_src[n] = as;
    a_dst[n] = ad;

    __half2 hp[16];
#pragma unroll
    for (int k = 0; k < 16; ++k) hp[k] = __floats2half2_rn(hv[2 * k], hv[2 * k + 1]);
    uint4* dst = (uint4*)(h2 + (size_t)n * 16);
    const uint4* srcp = (const uint4*)hp;
#pragma unroll
    for (int k = 0; k < 4; ++k) dst[k] = srcp[k];
}

// ---------------- kernel 3: fused LDS row assembly + gather; bin == block ----------------
// Lane map (R10-proven): es = l>>2 (0..15 edge subgroups), cg = l&3 (8 channels, uint4).
// 31.8 KB LDS + 1024 threads -> 2 blocks/CU -> 32 waves/CU (full slots).
__global__ __launch_bounds__(1024) void k_asm_gather(const uint2* __restrict__ part,
                                                     const int* __restrict__ pcur,
                                                     const __half2* __restrict__ h2,
                                                     const float* __restrict__ a_src,
                                                     const float* __restrict__ a_dst,
                                                     const float* __restrict__ bias,
                                                     const float* __restrict__ W_gate,
                                                     const float* __restrict__ b_gate,
                                                     float* __restrict__ oacc,
                                                     float* __restrict__ ge) {
    int b = blockIdx.x;
    int lo = b * BIN_W;
    if (lo >= N_NODES) return;
    int hi = lo + BIN_W; if (hi > N_NODES) hi = N_NODES;
    int nrow = hi - lo;
    __shared__ int lcur[BIN_W];
    __shared__ unsigned lbuck[BIN_W * PAD];   // 31.4 KB
    int t = threadIdx.x;
    if (t < BIN_W) lcur[t] = 0;
    __syncthreads();

    // ---- phase 1: assemble rows in LDS (own partition only, single sequential read) ----
    int cnt = pcur[b]; if (cnt > BIN_CAP) cnt = BIN_CAP;
    const uint2* p = part + (size_t)b * BIN_CAP;
    for (int i = t; i < cnt; i += 1024) {
        uint2 r = p[i];
        int li = (int)(r.x & 0xFFFF) - lo;
        unsigned s = r.x >> 16;
        unsigned short hb = __half_as_ushort(__float2half_rn(__uint_as_float(r.y)));
        int pos = atomicAdd(&lcur[li], 1);
        if (pos < PAD) lbuck[li * PAD + pos] = s | ((unsigned)hb << 16);
    }
    __syncthreads();

    // ---- phase 2: wave-per-node gather from LDS rows ----
    int l = t & 63, wl = t >> 6;   // 16 waves
    int es = l >> 2;               // edge subgroup 0..15
    int cg = l & 3;                // channel group 0..3 (8 halves = one dwordx4)

    for (int li = wl; li < nrow; li += 16) {
        int n = lo + li;
        int deg_full = lcur[li];
        int degc = deg_full < PAD ? deg_full : PAD;
        float adst_n = a_dst[n];
        const unsigned* row = lbuck + li * PAD;

        float c0 = 0.f, c1 = 0.f, c2 = 0.f, c3 = 0.f, c4 = 0.f, c5 = 0.f, c6 = 0.f, c7 = 0.f;
        float wsum = 0.f, aevsum = 0.f;
        int j = es;
        for (; j + 16 < degc; j += 32) {
            unsigned p0 = row[j], p1 = row[j + 16];
            int s0 = p0 & 0xFFFF, s1 = p1 & 0xFFFF;
            float aev0 = __half2float(__ushort_as_half((unsigned short)(p0 >> 16)));
            float aev1 = __half2float(__ushort_as_half((unsigned short)(p1 >> 16)));
            float as0 = a_src[s0], as1 = a_src[s1];
            const uint4 u0 = *(const uint4*)(h2 + (size_t)s0 * 16 + cg * 4);
            const uint4 u1 = *(const uint4*)(h2 + (size_t)s1 * 16 + cg * 4);
            float a0 = as0 + adst_n + aev0; a0 = a0 > 0.f ? a0 : NEG_SLOPE * a0;
            float a1 = as1 + adst_n + aev1; a1 = a1 > 0.f ? a1 : NEG_SLOPE * a1;
            float w0 = __expf(a0), w1 = __expf(a1);
            wsum += w0 + w1; aevsum += aev0 + aev1;
            float2 f;
            f = __half22float2(*(const __half2*)&u0.x); c0 += w0 * f.x; c1 += w0 * f.y;
            f = __half22float2(*(const __half2*)&u0.y); c2 += w0 * f.x; c3 += w0 * f.y;
            f = __half22float2(*(const __half2*)&u0.z); c4 += w0 * f.x; c5 += w0 * f.y;
            f = __half22float2(*(const __half2*)&u0.w); c6 += w0 * f.x; c7 += w0 * f.y;
            f = __half22float2(*(const __half2*)&u1.x); c0 += w1 * f.x; c1 += w1 * f.y;
            f = __half22float2(*(const __half2*)&u1.y); c2 += w1 * f.x; c3 += w1 * f.y;
            f = __half22float2(*(const __half2*)&u1.z); c4 += w1 * f.x; c5 += w1 * f.y;
            f = __half22float2(*(const __half2*)&u1.w); c6 += w1 * f.x; c7 += w1 * f.y;
        }
        if (j < degc) {
            unsigned p0 = row[j];
            int s0 = p0 & 0xFFFF;
            float aev0 = __half2float(__ushort_as_half((unsigned short)(p0 >> 16)));
            float a0 = a_src[s0] + adst_n + aev0; a0 = a0 > 0.f ? a0 : NEG_SLOPE * a0;
            float w0 = __expf(a0);
            const uint4 u0 = *(const uint4*)(h2 + (size_t)s0 * 16 + cg * 4);
            wsum += w0; aevsum += aev0;
            float2 f;
            f = __half22float2(*(const __half2*)&u0.x); c0 += w0 * f.x; c1 += w0 * f.y;
            f = __half22float2(*(const __half2*)&u0.y); c2 += w0 * f.x; c3 += w0 * f.y;
            f = __half22float2(*(const __half2*)&u0.z); c4 += w0 * f.x; c5 += w0 * f.y;
            f = __half22float2(*(const __half2*)&u0.w); c6 += w0 * f.x; c7 += w0 * f.y;
        }

#pragma unroll
        for (int m = 4; m <= 32; m <<= 1) {
            c0 += __shfl_xor(c0, m); c1 += __shfl_xor(c1, m);
            c2 += __shfl_xor(c2, m); c3 += __shfl_xor(c3, m);
            c4 += __shfl_xor(c4, m); c5 += __shfl_xor(c5, m);
            c6 += __shfl_xor(c6, m); c7 += __shfl_xor(c7, m);
            wsum += __shfl_xor(wsum, m); aevsum += __shfl_xor(aevsum, m);
        }

        float dgm = deg_full > 1 ? (float)deg_full : 1.f;
        float al = a_src[n] + adst_n + aevsum / dgm;
        al = al > 0.f ? al : NEG_SLOPE * al;
        float el = __expf(al);
        float zi = 1.f / (wsum + el + SM_EPS);

        if (es == 0) {          // lanes 0..3, 8 channels each
            const uint4 un = *(const uint4*)(h2 + (size_t)n * 16 + cg * 4);
            float hn[8];
            float2 f;
            f = __half22float2(*(const __half2*)&un.x); hn[0] = f.x; hn[1] = f.y;
            f = __half22float2(*(const __half2*)&un.y); hn[2] = f.x; hn[3] = f.y;
            f = __half22float2(*(const __half2*)&un.z); hn[4] = f.x; hn[5] = f.y;
            f = __half22float2(*(const __half2*)&un.w); hn[6] = f.x; hn[7] = f.y;
            const float4 bva = *(const float4*)(bias + cg * 8);
            const float4 bvb = *(const float4*)(bias + cg * 8 + 4);
            float4 va, vb;
            va.x = (c0 + el * hn[0]) * zi + bva.x;
            va.y = (c1 + el * hn[1]) * zi + bva.y;
            va.z = (c2 + el * hn[2]) * zi + bva.z;
            va.w = (c3 + el * hn[3]) * zi + bva.w;
            vb.x = (c4 + el * hn[4]) * zi + bvb.x;
            vb.y = (c5 + el * hn[5]) * zi + bvb.y;
            vb.z = (c6 + el * hn[6]) * zi + bvb.z;
            vb.w = (c7 + el * hn[7]) * zi + bvb.w;
            va.x = va.x > 0.f ? va.x : 0.f;  va.y = va.y > 0.f ? va.y : 0.f;
            va.z = va.z > 0.f ? va.z : 0.f;  va.w = va.w > 0.f ? va.w : 0.f;
            vb.x = vb.x > 0.f ? vb.x : 0.f;  vb.y = vb.y > 0.f ? vb.y : 0.f;
            vb.z = vb.z > 0.f ? vb.z : 0.f;  vb.w = vb.w > 0.f ? vb.w : 0.f;
            *(float4*)(oacc + (size_t)n * 32 + cg * 8) = va;
            *(float4*)(oacc + (size_t)n * 32 + cg * 8 + 4) = vb;
            const float4 wga = *(const float4*)(W_gate + cg * 8);
            const float4 wgb = *(const float4*)(W_gate + cg * 8 + 4);
            float g = va.x * wga.x + va.y * wga.y + va.z * wga.z + va.w * wga.w
                    + vb.x * wgb.x + vb.y * wgb.y + vb.z * wgb.z + vb.w * wgb.w;
            g += __shfl_xor(g, 1);
            g += __shfl_xor(g, 2);
            if (cg == 0) {
                g += b_gate[0];
                ge[n] = __expf(g);
            }
        }
    }
}

// ---------------- kernel 4: per-graph pooling + output head (inline boundary search) ----------------
__global__ __launch_bounds__(256) void k_pool_out(const float* __restrict__ oacc,
                                                  const float* __restrict__ ge,
                                                  const int* __restrict__ batch,
                                                  const float* __restrict__ W_out,
                                                  const float* __restrict__ b_out,
                                                  float* __restrict__ out) {
    int g = blockIdx.x;
    int t = threadIdx.x;
    __shared__ int sbound[2];
    if (t < 2) {
        int target = g + t;
        int lo = 0, hi = N_NODES;
        if (target >= N_GRAPHS) lo = N_NODES;
        else {
            while (lo < hi) {
                int mid = (lo + hi) >> 1;
                if (batch[mid] < target) lo = mid + 1; else hi = mid;
            }
        }
        sbound[t] = lo;
    }
    __syncthreads();
    int beg = sbound[0], end = sbound[1];
    __shared__ float swz[4];
    __shared__ float part[8][32];
    __shared__ float sgz;

    float s = 0.f;
    for (int n = beg + t; n < end; n += 256) s += ge[n];
#pragma unroll
    for (int ofs = 32; ofs > 0; ofs >>= 1) s += __shfl_down(s, ofs);
    if ((t & 63) == 0) swz[t >> 6] = s;
    __syncthreads();
    if (t == 0) sgz = swz[0] + swz[1] + swz[2] + swz[3];
    __syncthreads();
    float gz = sgz;

    int c = t & 31, ng = t >> 5;
    float acc = 0.f;
    for (int n = beg + ng; n < end; n += 8)
        acc += oacc[(size_t)n * 32 + c] * ge[n];
    part[ng][c] = acc;
    __syncthreads();
    if (t < 32) {
        float p = 0.f;
#pragma unroll
        for (int i = 0; i < 8; ++i) p += part[i][t];
        p /= (gz + SM_EPS);
        float o = p * W_out[t];
#pragma unroll
        for (int ofs = 16; ofs > 0; ofs >>= 1) o += __shfl_down(o, ofs);
        if (t == 0) out[g] = 1.f / (1.f + __expf(-(o + b_out[0])));
    }
}

extern "C" void kernel_launch(void* const* d_in, const int* in_sizes, int n_in,
                              void* d_out, int out_size, void* d_ws, size_t ws_size,
                              hipStream_t stream) {
    const float* x        = (const float*)d_in[0];
    const int*   ei       = (const int*)  d_in[1];
    const float* ea       = (const float*)d_in[2];
    const int*   batch    = (const int*)  d_in[3];
    const float* W        = (const float*)d_in[4];
    const float* att_src  = (const float*)d_in[5];
    const float* att_dst  = (const float*)d_in[6];
    const float* W_edge   = (const float*)d_in[7];
    const float* att_edge = (const float*)d_in[8];
    const float* bias     = (const float*)d_in[9];
    const float* W_gate   = (const float*)d_in[10];
    const float* b_gate   = (const float*)d_in[11];
    const float* W_out    = (const float*)d_in[12];
    const float* b_out    = (const float*)d_in[13];
    float* out = (float*)d_out;

    // workspace layout
    char* wsb = (char*)d_ws;
    uint2*    part_  = (uint2*)wsb;                                // NBIN*BIN_CAP uint2 = 15.5 MB
    __half2*  h2     = (__half2*)(part_ + (size_t)NBIN * BIN_CAP); // 16N half2 = 3.2 MB
    float*    a_src  = (float*)(h2 + (size_t)16 * N_NODES);        // N
    float*    a_dst  = a_src + N_NODES;                            // N
    float*    ge     = a_dst + N_NODES;                            // N
    float*    oacc   = ge + N_NODES;                               // 32N
    int*      pcur   = (int*)(oacc + (size_t)32 * N_NODES);        // NBIN (zeroed)

    hipMemsetAsync(pcur, 0, NBIN * sizeof(int), stream);

    const int B = 256;
    k_part_direct<<<PART_BLOCKS, B, 0, stream>>>(ei, ea, W_edge, att_edge, part_, pcur);
    k_node<<<(N_NODES + B - 1) / B, B, 0, stream>>>(x, W, att_src, att_dst, h2, a_src, a_dst);
    k_asm_gather<<<NBIN, 1024, 0, stream>>>(part_, pcur, h2, a_src, a_dst, bias,
                                            W_gate, b_gate, oacc, ge);
    k_pool_out<<<N_GRAPHS, B, 0, stream>>>(oacc, ge, batch, W_out, b_out, out);
}